// Round 1
// baseline (1386.714 us; speedup 1.0000x reference)
//
#include <hip/hip_runtime.h>
#include <math.h>

#define F 20
#define D 16
#define VOCAB 50000
#define V_TOTAL (F * VOCAB)      // 1,000,000
#define NPAIRS (F * (F - 1) / 2) // 190

__global__ __launch_bounds__(256) void ffm_kernel(
    const int* __restrict__ x,         // (B, F) int32
    const float* __restrict__ Wlin,    // (V, 1)
    const float* __restrict__ Wcross,  // (F, V, D)
    const float* __restrict__ bias,    // (1,)
    float* __restrict__ out)           // (B,)
{
    const int b = blockIdx.x;
    const int t = threadIdx.x;

    __shared__ int s_xo[F];
    __shared__ unsigned char s_i[NPAIRS];
    __shared__ unsigned char s_j[NPAIRS];
    __shared__ float s_red[4];

    if (t < F) s_xo[t] = x[b * F + t] + t * VOCAB;
    if (t < NPAIRS) {
        int p = t, i = 0;
        while (p >= F - 1 - i) { p -= F - 1 - i; ++i; }
        s_i[t] = (unsigned char)i;
        s_j[t] = (unsigned char)(i + 1 + p);
    }
    __syncthreads();

    float partial = 0.f;

    // linear term: threads 0..19
    if (t < F) partial += Wlin[s_xo[t]];

    // cross term: 190 pairs x 4 quad-chunks = 760 tasks
    // task -> pair p = task>>2, chunk d4 = task&3 (float4 within the 16-dim embedding)
    #pragma unroll
    for (int it = 0; it < 3; ++it) {
        int task = it * 256 + t;
        if (task < NPAIRS * 4) {
            int p  = task >> 2;
            int d4 = task & 3;
            int i = s_i[p];
            int j = s_j[p];
            const float4* A = (const float4*)(Wcross + ((size_t)j * V_TOTAL + s_xo[i]) * D);
            const float4* B = (const float4*)(Wcross + ((size_t)i * V_TOTAL + s_xo[j]) * D);
            float4 a4 = A[d4];
            float4 b4 = B[d4];
            partial += a4.x * b4.x + a4.y * b4.y + a4.z * b4.z + a4.w * b4.w;
        }
    }

    // wave reduce (64 lanes)
    #pragma unroll
    for (int off = 32; off > 0; off >>= 1)
        partial += __shfl_down(partial, off, 64);

    int wave = t >> 6;
    if ((t & 63) == 0) s_red[wave] = partial;
    __syncthreads();

    if (t == 0) {
        float s = s_red[0] + s_red[1] + s_red[2] + s_red[3] + bias[0];
        out[b] = 1.f / (1.f + expf(-s));
    }
}

extern "C" void kernel_launch(void* const* d_in, const int* in_sizes, int n_in,
                              void* d_out, int out_size, void* d_ws, size_t ws_size,
                              hipStream_t stream) {
    const int*   x      = (const int*)d_in[0];
    const float* Wlin   = (const float*)d_in[1];
    const float* Wcross = (const float*)d_in[2];
    const float* bias   = (const float*)d_in[3];
    float* out = (float*)d_out;

    ffm_kernel<<<dim3(out_size), dim3(256), 0, stream>>>(x, Wlin, Wcross, bias, out);
}

// Round 2
// 1376.057 us; speedup vs baseline: 1.0077x; 1.0077x over previous
//
#include <hip/hip_runtime.h>
#include <math.h>

#define F 20
#define D 16
#define VOCAB 50000
#define V_TOTAL (F * VOCAB)      // 1,000,000
#define NPAIRS (F * (F - 1) / 2) // 190
#define EPB 2                    // batch elements per block

__global__ __launch_bounds__(256) void ffm_kernel(
    const int* __restrict__ x,         // (B, F) int32
    const float* __restrict__ Wlin,    // (V, 1)
    const float* __restrict__ Wcross,  // (F, V, D)
    const float* __restrict__ bias,    // (1,)
    float* __restrict__ out,           // (B,)
    int B)
{
    const int b0 = blockIdx.x * EPB;
    const int t  = threadIdx.x;

    __shared__ int s_xo[EPB][F];
    __shared__ unsigned char s_i[NPAIRS];
    __shared__ unsigned char s_j[NPAIRS];
    __shared__ float s_red[4][EPB];

    if (t < EPB * F) {
        int e = t / F, f = t % F;
        int bb = b0 + e;
        s_xo[e][f] = (bb < B ? x[bb * F + f] : 0) + f * VOCAB;
    }
    if (t < NPAIRS) {
        int p = t, i = 0;
        while (p >= F - 1 - i) { p -= F - 1 - i; ++i; }
        s_i[t] = (unsigned char)i;
        s_j[t] = (unsigned char)(i + 1 + p);
    }
    __syncthreads();

    float partial0 = 0.f;
    float partial1 = 0.f;

    // linear term: threads 0..39 (20 per element)
    if (t < EPB * F) {
        int e = t / F, f = t % F;
        float lv = Wlin[s_xo[e][f]];
        if (e == 0) partial0 += lv; else partial1 += lv;
    }

    // cross term: per element, 190 pairs x 4 quad-chunks = 760 tasks over 3 iters.
    // Both elements handled in the same iteration -> 4 independent loads per iter,
    // 12 per thread total, all address-ready before any use.
    #pragma unroll
    for (int it = 0; it < 3; ++it) {
        int task = it * 256 + t;
        bool act = task < NPAIRS * 4;
        int p  = act ? (task >> 2) : 0;
        int d4 = task & 3;
        int i = s_i[p];
        int j = s_j[p];

        const float4* A0 = (const float4*)(Wcross + ((size_t)j * V_TOTAL + s_xo[0][i]) * D);
        const float4* B0 = (const float4*)(Wcross + ((size_t)i * V_TOTAL + s_xo[0][j]) * D);
        const float4* A1 = (const float4*)(Wcross + ((size_t)j * V_TOTAL + s_xo[1][i]) * D);
        const float4* B1 = (const float4*)(Wcross + ((size_t)i * V_TOTAL + s_xo[1][j]) * D);

        if (act) {
            float4 a0 = A0[d4];
            float4 c0 = B0[d4];
            float4 a1 = A1[d4];
            float4 c1 = B1[d4];
            partial0 += a0.x * c0.x + a0.y * c0.y + a0.z * c0.z + a0.w * c0.w;
            partial1 += a1.x * c1.x + a1.y * c1.y + a1.z * c1.z + a1.w * c1.w;
        }
    }

    // wave reduce (64 lanes), both accumulators
    #pragma unroll
    for (int off = 32; off > 0; off >>= 1) {
        partial0 += __shfl_down(partial0, off, 64);
        partial1 += __shfl_down(partial1, off, 64);
    }

    int wave = t >> 6;
    if ((t & 63) == 0) {
        s_red[wave][0] = partial0;
        s_red[wave][1] = partial1;
    }
    __syncthreads();

    if (t < EPB && (b0 + t) < B) {
        float s = s_red[0][t] + s_red[1][t] + s_red[2][t] + s_red[3][t] + bias[0];
        out[b0 + t] = 1.f / (1.f + expf(-s));
    }
}

extern "C" void kernel_launch(void* const* d_in, const int* in_sizes, int n_in,
                              void* d_out, int out_size, void* d_ws, size_t ws_size,
                              hipStream_t stream) {
    const int*   x      = (const int*)d_in[0];
    const float* Wlin   = (const float*)d_in[1];
    const float* Wcross = (const float*)d_in[2];
    const float* bias   = (const float*)d_in[3];
    float* out = (float*)d_out;

    int blocks = (out_size + EPB - 1) / EPB;
    ffm_kernel<<<dim3(blocks), dim3(256), 0, stream>>>(x, Wlin, Wcross, bias, out, out_size);
}